// Round 5
// baseline (865.921 us; speedup 1.0000x reference)
//
#include <hip/hip_runtime.h>

// OnlineDenoisingAutoencoder: LSTM(B=2048, T=2048, in=1, proj=16, H=32)
// R11: in-wave dual-chain software pipeline. Structural law from R6-R10:
// wall = 2048 x (h->h' critical path); R6's 779-cyc chain (incl. ~150-200
// LDS round trip + ~60 trans) is the floor, and co-resident waves can NOT
// fill each other's stalls (R7 phase-locked 74.6% busy; R10 stagger only
// 796->770). The only deterministic filler is a second INDEPENDENT
// recurrence in the same instruction stream. Each wave = R7's proven
// gate-split layout (64 lanes = 1 batch, 2 gates/lane, permlane32_swap
// exchange) but carries TWO batches time-interleaved:
//   dotsA | gatesA | dotsB(covers A trans) | updateA+publishA |
//   gatesB+updateB+publishB(covers A gather) | reduceA+reduceB(covers B gather)
// 1024 waves (1/SIMD). Weights + input-collapse constants shared across the
// two batches (same lane->gate map) -> per-pair issue ~660-700 cyc, every
// latency element followed by >=100 cyc of independent issue.
// History: R6 665us (chain floor, 237 exposed); R7 796 (2/SIMD phase-lock);
// R8 728 (reg butterfly +issue); R9 1264 (K-split exchange 3x static);
// R10 770 (stagger doesn't stick). Lesson: hide latency IN-wave.

#define BB 2048
#define TT 2048
#define HH 32

typedef _Float16 h2 __attribute__((ext_vector_type(2)));
typedef unsigned int uint2v __attribute__((ext_vector_type(2)));

__device__ __forceinline__ float gate_eval(float x, float m, float a, float b) {
    // a * (1 / (1 + 2^(m*x))) + b ; sigmoid: m=-log2e,a=1,b=0 ; tanh: m=-2log2e,a=2,b=-1
    float e = __builtin_amdgcn_exp2f(x * m);
    float r = __builtin_amdgcn_rcpf(1.0f + e);
    return fmaf(a, r, b);
}

template <int CTRL>
__device__ __forceinline__ float dpp_add(float v) {
    int s = __builtin_amdgcn_update_dpp(0, __float_as_int(v), CTRL, 0xf, 0xf, true);
    return v + __int_as_float(s);
}

struct HVec { h2 v[16]; };

__device__ __forceinline__ HVec gather_h(const _Float16* base) {
    const float4* p = (const float4*)base;   // 64 B = 4 x ds_read_b128 (broadcast)
    float4 q0 = p[0], q1 = p[1], q2 = p[2], q3 = p[3];
    HVec r;
    r.v[0]  = __builtin_bit_cast(h2, q0.x); r.v[1]  = __builtin_bit_cast(h2, q0.y);
    r.v[2]  = __builtin_bit_cast(h2, q0.z); r.v[3]  = __builtin_bit_cast(h2, q0.w);
    r.v[4]  = __builtin_bit_cast(h2, q1.x); r.v[5]  = __builtin_bit_cast(h2, q1.y);
    r.v[6]  = __builtin_bit_cast(h2, q1.z); r.v[7]  = __builtin_bit_cast(h2, q1.w);
    r.v[8]  = __builtin_bit_cast(h2, q2.x); r.v[9]  = __builtin_bit_cast(h2, q2.y);
    r.v[10] = __builtin_bit_cast(h2, q2.z); r.v[11] = __builtin_bit_cast(h2, q2.w);
    r.v[12] = __builtin_bit_cast(h2, q3.x); r.v[13] = __builtin_bit_cast(h2, q3.y);
    r.v[14] = __builtin_bit_cast(h2, q3.z); r.v[15] = __builtin_bit_cast(h2, q3.w);
    return r;
}

__global__ __launch_bounds__(256) void lstm_fused_kernel(
    const float* __restrict__ x_seq,  // [B,T,1]
    const float* __restrict__ Wp,     // [16,1]
    const float* __restrict__ bp,     // [16]
    const float* __restrict__ W_ih,   // [128,16]
    const float* __restrict__ W_hh,   // [128,32]
    const float* __restrict__ b_ih,   // [128]
    const float* __restrict__ b_hh,   // [128]
    const float* __restrict__ Wo,     // [1,32]
    const float* __restrict__ bo,     // [1]
    float* __restrict__ out)          // [B,T,1] fp32
{
    const int tid  = threadIdx.x;
    const int wave = tid >> 6;
    const int lane = tid & 63;
    const int half = lane >> 5;      // gate-pair selector: 0 -> (i,g), 1 -> (f,o)
    const int j    = lane & 31;      // hidden index this lane owns
    const int b0   = blockIdx.x * 8 + wave * 2;   // batches b0 (A), b0+1 (B)

    // PyTorch gate row order: i=[0,32), f=[32,64), g=[64,96), o=[96,128)
    const int rA = half * HH + j;            // i (half0) or f (half1) -- sigmoid
    const int rB = 2 * HH + half * HH + j;   // g (half0, tanh) or o (half1, sigmoid)

    // ---- W_hh rows (2 gates per lane), shared by both batches ----
    h2 wA[16], wB[16];
    {
        const float2* pA = (const float2*)(W_hh + rA * HH);
        const float2* pB = (const float2*)(W_hh + rB * HH);
#pragma unroll
        for (int k = 0; k < 16; ++k) {
            float2 a = pA[k], q = pB[k];
            wA[k].x = (_Float16)a.x; wA[k].y = (_Float16)a.y;
            wB[k].x = (_Float16)q.x; wB[k].y = (_Float16)q.y;
        }
    }

    // ---- collapse input pipeline: gate pre-act = dot + x*xA_ + kA_ ----
    float xA_ = 0.f, kA_ = 0.f, xB_ = 0.f, kB_ = 0.f;
#pragma unroll
    for (int p = 0; p < 16; ++p) {
        float wpv = Wp[p], bpv = bp[p];
        float wa = W_ih[rA * 16 + p], wb = W_ih[rB * 16 + p];
        xA_ = fmaf(wa, wpv, xA_);  kA_ = fmaf(wa, bpv, kA_);
        xB_ = fmaf(wb, wpv, xB_);  kB_ = fmaf(wb, bpv, kB_);
    }
    kA_ += b_ih[rA] + b_hh[rA];
    kB_ += b_ih[rB] + b_hh[rB];

    const float LOG2E = 1.44269504088896340736f;
    // per-lane gate-B nonlinearity constants: tanh (half0) vs sigmoid (half1)
    const float mB = half ? -LOG2E : -2.0f * LOG2E;
    const float aB = half ? 1.0f   : 2.0f;
    const float bB = half ? 0.0f   : -1.0f;

    const float woj = Wo[j];
    const float bo0 = bo[0];

    // per-(wave,batch,half) h replica, fp16, 64 B each
    __shared__ __align__(16) _Float16 hsh[4][2][2][HH];
    _Float16* baseA = &hsh[wave][0][half][0];
    _Float16* baseB = &hsh[wave][1][half][0];
    baseA[j] = (_Float16)0.0f;
    baseB[j] = (_Float16)0.0f;

    float cA = 0.0f, cB = 0.0f;
    const float* xpA = x_seq + (size_t)b0 * TT;
    const float* xpB = x_seq + (size_t)(b0 + 1) * TT;
    float* opA = out + (size_t)b0 * TT;
    float* opB = out + (size_t)(b0 + 1) * TT;

    HVec vA = gather_h(baseA);            // zeros (same-wave DS order)
    HVec vB = gather_h(baseB);
    float4 x4A = *(const float4*)(xpA);
    float4 x4B = *(const float4*)(xpB);

    for (int t = 0; t < TT; t += 4) {
        const int tn = (t + 4 < TT) ? (t + 4) : t;
        float4 x4An = *(const float4*)(xpA + tn);   // prefetch next group
        float4 x4Bn = *(const float4*)(xpB + tn);
        float outA[4], outB[4];
#pragma unroll
        for (int u = 0; u < 4; ++u) {
            float xvA = (u == 0) ? x4A.x : (u == 1) ? x4A.y : (u == 2) ? x4A.z : x4A.w;
            float xvB = (u == 0) ? x4B.x : (u == 1) ? x4B.y : (u == 2) ? x4B.z : x4B.w;

            // ---- batch A: gate dots ----
            float sAa0 = kA_, sAa1 = xvA * xA_;
            float sAb0 = kB_, sAb1 = xvA * xB_;
#pragma unroll
            for (int k = 0; k < 16; k += 2) {
                h2 h0 = vA.v[k], h1 = vA.v[k + 1];
                sAa0 = __builtin_amdgcn_fdot2(wA[k],     h0, sAa0, false);
                sAb0 = __builtin_amdgcn_fdot2(wB[k],     h0, sAb0, false);
                sAa1 = __builtin_amdgcn_fdot2(wA[k + 1], h1, sAa1, false);
                sAb1 = __builtin_amdgcn_fdot2(wB[k + 1], h1, sAb1, false);
            }
            // ---- batch A: nonlinearities (trans chain pends...) ----
            float AactA = gate_eval(sAa0 + sAa1, -LOG2E, 1.0f, 0.0f);
            float BactA = gate_eval(sAb0 + sAb1, mB, aB, bB);

            // ---- batch B: gate dots (independent issue covers A's trans) ----
            float sBa0 = kA_, sBa1 = xvB * xA_;
            float sBb0 = kB_, sBb1 = xvB * xB_;
#pragma unroll
            for (int k = 0; k < 16; k += 2) {
                h2 h0 = vB.v[k], h1 = vB.v[k + 1];
                sBa0 = __builtin_amdgcn_fdot2(wA[k],     h0, sBa0, false);
                sBb0 = __builtin_amdgcn_fdot2(wB[k],     h0, sBb0, false);
                sBa1 = __builtin_amdgcn_fdot2(wA[k + 1], h1, sBa1, false);
                sBb1 = __builtin_amdgcn_fdot2(wB[k + 1], h1, sBb1, false);
            }

            // ---- batch A: exchange + cell update + publish ----
            uint2v eAA = __builtin_amdgcn_permlane32_swap(
                __float_as_uint(AactA), __float_as_uint(AactA), false, false);
            uint2v eBA = __builtin_amdgcn_permlane32_swap(
                __float_as_uint(BactA), __float_as_uint(BactA), false, false);
            float ivA = __uint_as_float(eAA[0]);
            float fvA = __uint_as_float(eAA[1]);
            float gvA = __uint_as_float(eBA[0]);
            float ovA = __uint_as_float(eBA[1]);
            cA = fmaf(fvA, cA, ivA * gvA);
            float thA = gate_eval(cA, -2.0f * LOG2E, 2.0f, -1.0f); // tanh(cA)
            float hAs = ovA * thA;
            baseA[j] = (_Float16)hAs;
            vA = gather_h(baseA);        // read latency covered by B's tail below

            // ---- batch B: nonlinearities + exchange + update + publish ----
            float AactB = gate_eval(sBa0 + sBa1, -LOG2E, 1.0f, 0.0f);
            float BactB = gate_eval(sBb0 + sBb1, mB, aB, bB);
            uint2v eAB = __builtin_amdgcn_permlane32_swap(
                __float_as_uint(AactB), __float_as_uint(AactB), false, false);
            uint2v eBB = __builtin_amdgcn_permlane32_swap(
                __float_as_uint(BactB), __float_as_uint(BactB), false, false);
            float ivB = __uint_as_float(eAB[0]);
            float fvB = __uint_as_float(eAB[1]);
            float gvB = __uint_as_float(eBB[0]);
            float ovB = __uint_as_float(eBB[1]);
            cB = fmaf(fvB, cB, ivB * gvB);
            float thB = gate_eval(cB, -2.0f * LOG2E, 2.0f, -1.0f); // tanh(cB)
            float hBs = ovB * thB;
            baseB[j] = (_Float16)hBs;
            vB = gather_h(baseB);        // read latency covered by reduces below

            // ---- output reductions (fill both gathers' latency) ----
            float poA = woj * hAs;
            poA = dpp_add<0x111>(poA);
            poA = dpp_add<0x112>(poA);
            poA = dpp_add<0x114>(poA);
            poA = dpp_add<0x118>(poA);
            poA = dpp_add<0x142>(poA);
            outA[u] = poA + bo0;

            float poB = woj * hBs;
            poB = dpp_add<0x111>(poB);
            poB = dpp_add<0x112>(poB);
            poB = dpp_add<0x114>(poB);
            poB = dpp_add<0x118>(poB);
            poB = dpp_add<0x142>(poB);
            outB[u] = poB + bo0;
        }
        if (lane == 31) {
            *(float4*)(opA + t) = make_float4(outA[0], outA[1], outA[2], outA[3]);
            *(float4*)(opB + t) = make_float4(outB[0], outB[1], outB[2], outB[3]);
        }
        x4A = x4An;
        x4B = x4Bn;
    }
}

extern "C" void kernel_launch(void* const* d_in, const int* in_sizes, int n_in,
                              void* d_out, int out_size, void* d_ws, size_t ws_size,
                              hipStream_t stream) {
    const float* x_seq = (const float*)d_in[0];
    const float* Wp    = (const float*)d_in[1];
    const float* bp    = (const float*)d_in[2];
    const float* W_ih  = (const float*)d_in[3];
    const float* W_hh  = (const float*)d_in[4];
    const float* b_ih  = (const float*)d_in[5];
    const float* b_hh  = (const float*)d_in[6];
    const float* Wo    = (const float*)d_in[7];
    const float* bo    = (const float*)d_in[8];
    float* out = (float*)d_out;

    dim3 grid(BB / 8);   // 4 waves/block, 2 batches/wave -> 1024 waves (1/SIMD)
    dim3 block(256);
    lstm_fused_kernel<<<grid, block, 0, stream>>>(
        x_seq, Wp, bp, W_ih, W_hh, b_ih, b_hh, Wo, bo, out);
}

// Round 6
// 840.195 us; speedup vs baseline: 1.0306x; 1.0306x over previous
//
#include <hip/hip_runtime.h>

// OnlineDenoisingAutoencoder: LSTM(B=2048, T=2048, in=1, proj=16, H=32)
// R12 = R11 (in-wave dual-chain pipeline) + sched_barrier(0) region fences.
// R11 post-mortem: wall/pair = 1034 cyc = exactly 2x a solo 517-cyc chain,
// VGPR=64 -> the compiler SERIALIZED the two chains (register-pressure-min
// scheduling); the decomposition was right (issue/batch 342 ~= predicted),
// the schedule wasn't. Fix: pin a 7-region pipeline per step with
// __builtin_amdgcn_sched_barrier(0) (compile-time fence, no runtime cost):
//   P1 dotsA+exp2A | P2 dotsB+exp2B | P3 finA,xchgA,cA,exp2(cA)
//   | P4 finB,xchgB,cB,exp2(cB) | P5 tanhA,hA,publishA,gatherA
//   | P6 tanhB,hB,publishB,gatherB,reduceA | P7 reduceB
// Every latency element (trans, both LDS round trips) is followed by
// >=100 cyc of fenced independent issue. Also: gate weights/consts
// pre-scaled by the exp2 multiplier (-log2e sigmoid rows, -2log2e g row)
// so each gate nonlinearity drops its leading v_mul.
// Tell for success: VGPR ~100-130 (two live chains), busy ~85-92%.
// History: R6 665 (single chain, 237 stall); R7 796 (phase-locked 2/SIMD);
// R8 728 / R9 1264 (reg-exchange 2-3x static cost); R10 770 (stagger
// doesn't stick); R11 882 (compiler serialized the dual chain).

#define BB 2048
#define TT 2048
#define HH 32

typedef _Float16 h2 __attribute__((ext_vector_type(2)));
typedef unsigned int uint2v __attribute__((ext_vector_type(2)));

#define SB() __builtin_amdgcn_sched_barrier(0)

template <int CTRL>
__device__ __forceinline__ float dpp_add(float v) {
    int s = __builtin_amdgcn_update_dpp(0, __float_as_int(v), CTRL, 0xf, 0xf, true);
    return v + __int_as_float(s);
}

struct HVec { h2 v[16]; };

__device__ __forceinline__ HVec gather_h(const _Float16* base) {
    const float4* p = (const float4*)base;   // 64 B = 4 x ds_read_b128 (broadcast)
    float4 q0 = p[0], q1 = p[1], q2 = p[2], q3 = p[3];
    HVec r;
    r.v[0]  = __builtin_bit_cast(h2, q0.x); r.v[1]  = __builtin_bit_cast(h2, q0.y);
    r.v[2]  = __builtin_bit_cast(h2, q0.z); r.v[3]  = __builtin_bit_cast(h2, q0.w);
    r.v[4]  = __builtin_bit_cast(h2, q1.x); r.v[5]  = __builtin_bit_cast(h2, q1.y);
    r.v[6]  = __builtin_bit_cast(h2, q1.z); r.v[7]  = __builtin_bit_cast(h2, q1.w);
    r.v[8]  = __builtin_bit_cast(h2, q2.x); r.v[9]  = __builtin_bit_cast(h2, q2.y);
    r.v[10] = __builtin_bit_cast(h2, q2.z); r.v[11] = __builtin_bit_cast(h2, q2.w);
    r.v[12] = __builtin_bit_cast(h2, q3.x); r.v[13] = __builtin_bit_cast(h2, q3.y);
    r.v[14] = __builtin_bit_cast(h2, q3.z); r.v[15] = __builtin_bit_cast(h2, q3.w);
    return r;
}

__global__ __launch_bounds__(256) void lstm_fused_kernel(
    const float* __restrict__ x_seq,  // [B,T,1]
    const float* __restrict__ Wp,     // [16,1]
    const float* __restrict__ bp,     // [16]
    const float* __restrict__ W_ih,   // [128,16]
    const float* __restrict__ W_hh,   // [128,32]
    const float* __restrict__ b_ih,   // [128]
    const float* __restrict__ b_hh,   // [128]
    const float* __restrict__ Wo,     // [1,32]
    const float* __restrict__ bo,     // [1]
    float* __restrict__ out)          // [B,T,1] fp32
{
    const int tid  = threadIdx.x;
    const int wave = tid >> 6;
    const int lane = tid & 63;
    const int half = lane >> 5;      // gate-pair selector: 0 -> (i,g), 1 -> (f,o)
    const int j    = lane & 31;      // hidden index this lane owns
    const int b0   = blockIdx.x * 8 + wave * 2;   // batches b0 (A), b0+1 (B)

    // PyTorch gate row order: i=[0,32), f=[32,64), g=[64,96), o=[96,128)
    const int rA = half * HH + j;            // i (half0) or f (half1) -- sigmoid
    const int rB = 2 * HH + half * HH + j;   // g (half0, tanh) or o (half1, sigmoid)

    const float LOG2E = 1.44269504088896340736f;
    // exp2-argument multipliers folded into the weights (prescale):
    const float mA = -LOG2E;                       // sigmoid rows (i, f)
    const float mBv = half ? -LOG2E : -2.0f * LOG2E; // o : g
    // gate-B nonlinearity finish constants: tanh (half0) vs sigmoid (half1)
    const float aB = half ? 1.0f : 2.0f;
    const float bBc = half ? 0.0f : -1.0f;

    // ---- W_hh rows (2 gates per lane), PRESCALED, shared by both batches ----
    h2 wA[16], wB[16];
    {
        const float2* pA = (const float2*)(W_hh + rA * HH);
        const float2* pB = (const float2*)(W_hh + rB * HH);
#pragma unroll
        for (int k = 0; k < 16; ++k) {
            float2 a = pA[k], q = pB[k];
            wA[k].x = (_Float16)(a.x * mA);  wA[k].y = (_Float16)(a.y * mA);
            wB[k].x = (_Float16)(q.x * mBv); wB[k].y = (_Float16)(q.y * mBv);
        }
    }

    // ---- collapse input pipeline (prescaled): pre-act_s = dot_s + x*xA_ + kA_ ----
    float xA_ = 0.f, kA_ = 0.f, xB_ = 0.f, kB_ = 0.f;
#pragma unroll
    for (int p = 0; p < 16; ++p) {
        float wpv = Wp[p], bpv = bp[p];
        float wa = W_ih[rA * 16 + p], wb = W_ih[rB * 16 + p];
        xA_ = fmaf(wa, wpv, xA_);  kA_ = fmaf(wa, bpv, kA_);
        xB_ = fmaf(wb, wpv, xB_);  kB_ = fmaf(wb, bpv, kB_);
    }
    kA_ = (kA_ + b_ih[rA] + b_hh[rA]) * mA;
    kB_ = (kB_ + b_ih[rB] + b_hh[rB]) * mBv;
    xA_ *= mA;
    xB_ *= mBv;

    const float M2 = -2.0f * LOG2E;   // tanh(c) exp2 multiplier
    const float woj = Wo[j];
    const float bo0 = bo[0];

    // per-(wave,batch,half) h replica, fp16, 64 B each
    __shared__ __align__(16) _Float16 hsh[4][2][2][HH];
    _Float16* baseA = &hsh[wave][0][half][0];
    _Float16* baseB = &hsh[wave][1][half][0];
    baseA[j] = (_Float16)0.0f;
    baseB[j] = (_Float16)0.0f;

    float cA = 0.0f, cB = 0.0f;
    const float* xpA = x_seq + (size_t)b0 * TT;
    const float* xpB = x_seq + (size_t)(b0 + 1) * TT;
    float* opA = out + (size_t)b0 * TT;
    float* opB = out + (size_t)(b0 + 1) * TT;

    HVec vA = gather_h(baseA);            // zeros (same-wave DS order)
    HVec vB = gather_h(baseB);
    float4 x4A = *(const float4*)(xpA);
    float4 x4B = *(const float4*)(xpB);

    for (int t = 0; t < TT; t += 4) {
        const int tn = (t + 4 < TT) ? (t + 4) : t;
        float4 x4An = *(const float4*)(xpA + tn);   // prefetch next group
        float4 x4Bn = *(const float4*)(xpB + tn);
        float outA[4], outB[4];
#pragma unroll
        for (int u = 0; u < 4; ++u) {
            float xvA = (u == 0) ? x4A.x : (u == 1) ? x4A.y : (u == 2) ? x4A.z : x4A.w;
            float xvB = (u == 0) ? x4B.x : (u == 1) ? x4B.y : (u == 2) ? x4B.z : x4B.w;

            // ================= P1: dots A + exp2 A =================
            float sAa0 = kA_, sAa1 = xvA * xA_;
            float sAb0 = kB_, sAb1 = xvA * xB_;
#pragma unroll
            for (int k = 0; k < 16; k += 2) {
                h2 h0 = vA.v[k], h1 = vA.v[k + 1];
                sAa0 = __builtin_amdgcn_fdot2(wA[k],     h0, sAa0, false);
                sAb0 = __builtin_amdgcn_fdot2(wB[k],     h0, sAb0, false);
                sAa1 = __builtin_amdgcn_fdot2(wA[k + 1], h1, sAa1, false);
                sAb1 = __builtin_amdgcn_fdot2(wB[k + 1], h1, sAb1, false);
            }
            float eAa = __builtin_amdgcn_exp2f(sAa0 + sAa1);   // prescaled args
            float eAb = __builtin_amdgcn_exp2f(sAb0 + sAb1);
            SB();

            // ================= P2: dots B + exp2 B =================
            float sBa0 = kA_, sBa1 = xvB * xA_;
            float sBb0 = kB_, sBb1 = xvB * xB_;
#pragma unroll
            for (int k = 0; k < 16; k += 2) {
                h2 h0 = vB.v[k], h1 = vB.v[k + 1];
                sBa0 = __builtin_amdgcn_fdot2(wA[k],     h0, sBa0, false);
                sBb0 = __builtin_amdgcn_fdot2(wB[k],     h0, sBb0, false);
                sBa1 = __builtin_amdgcn_fdot2(wA[k + 1], h1, sBa1, false);
                sBb1 = __builtin_amdgcn_fdot2(wB[k + 1], h1, sBb1, false);
            }
            float eBa = __builtin_amdgcn_exp2f(sBa0 + sBa1);
            float eBb = __builtin_amdgcn_exp2f(sBb0 + sBb1);
            SB();

            // ===== P3: finish gates A, exchange, cA update, exp2(cA) =====
            float AactA = __builtin_amdgcn_rcpf(1.0f + eAa);            // sigmoid
            float BactA = fmaf(aB, __builtin_amdgcn_rcpf(1.0f + eAb), bBc);
            uint2v eAA = __builtin_amdgcn_permlane32_swap(
                __float_as_uint(AactA), __float_as_uint(AactA), false, false);
            uint2v eBA = __builtin_amdgcn_permlane32_swap(
                __float_as_uint(BactA), __float_as_uint(BactA), false, false);
            float ivA = __uint_as_float(eAA[0]);
            float fvA = __uint_as_float(eAA[1]);
            float gvA = __uint_as_float(eBA[0]);
            float ovA = __uint_as_float(eBA[1]);
            cA = fmaf(fvA, cA, ivA * gvA);
            float ecA = __builtin_amdgcn_exp2f(cA * M2);
            SB();

            // ===== P4: finish gates B, exchange, cB update, exp2(cB) =====
            float AactB = __builtin_amdgcn_rcpf(1.0f + eBa);
            float BactB = fmaf(aB, __builtin_amdgcn_rcpf(1.0f + eBb), bBc);
            uint2v eAB = __builtin_amdgcn_permlane32_swap(
                __float_as_uint(AactB), __float_as_uint(AactB), false, false);
            uint2v eBB = __builtin_amdgcn_permlane32_swap(
                __float_as_uint(BactB), __float_as_uint(BactB), false, false);
            float ivB = __uint_as_float(eAB[0]);
            float fvB = __uint_as_float(eAB[1]);
            float gvB = __uint_as_float(eBB[0]);
            float ovB = __uint_as_float(eBB[1]);
            cB = fmaf(fvB, cB, ivB * gvB);
            float ecB = __builtin_amdgcn_exp2f(cB * M2);
            SB();

            // ===== P5: tanh(cA) finish, hA, publish A, gather A =====
            float thA = fmaf(2.0f, __builtin_amdgcn_rcpf(1.0f + ecA), -1.0f);
            float hAs = ovA * thA;
            baseA[j] = (_Float16)hAs;
            vA = gather_h(baseA);
            SB();

            // ===== P6: tanh(cB) finish, hB, publish B, gather B; reduce A =====
            float thB = fmaf(2.0f, __builtin_amdgcn_rcpf(1.0f + ecB), -1.0f);
            float hBs = ovB * thB;
            baseB[j] = (_Float16)hBs;
            vB = gather_h(baseB);
            float poA = woj * hAs;
            poA = dpp_add<0x111>(poA);
            poA = dpp_add<0x112>(poA);
            poA = dpp_add<0x114>(poA);
            poA = dpp_add<0x118>(poA);
            poA = dpp_add<0x142>(poA);
            outA[u] = poA + bo0;
            SB();

            // ===== P7: reduce B =====
            float poB = woj * hBs;
            poB = dpp_add<0x111>(poB);
            poB = dpp_add<0x112>(poB);
            poB = dpp_add<0x114>(poB);
            poB = dpp_add<0x118>(poB);
            poB = dpp_add<0x142>(poB);
            outB[u] = poB + bo0;
        }
        if (lane == 31) {
            *(float4*)(opA + t) = make_float4(outA[0], outA[1], outA[2], outA[3]);
            *(float4*)(opB + t) = make_float4(outB[0], outB[1], outB[2], outB[3]);
        }
        x4A = x4An;
        x4B = x4Bn;
    }
}

extern "C" void kernel_launch(void* const* d_in, const int* in_sizes, int n_in,
                              void* d_out, int out_size, void* d_ws, size_t ws_size,
                              hipStream_t stream) {
    const float* x_seq = (const float*)d_in[0];
    const float* Wp    = (const float*)d_in[1];
    const float* bp    = (const float*)d_in[2];
    const float* W_ih  = (const float*)d_in[3];
    const float* W_hh  = (const float*)d_in[4];
    const float* b_ih  = (const float*)d_in[5];
    const float* b_hh  = (const float*)d_in[6];
    const float* Wo    = (const float*)d_in[7];
    const float* bo    = (const float*)d_in[8];
    float* out = (float*)d_out;

    dim3 grid(BB / 8);   // 4 waves/block, 2 batches/wave -> 1024 waves (1/SIMD)
    dim3 block(256);
    lstm_fused_kernel<<<grid, block, 0, stream>>>(
        x_seq, Wp, bp, W_ih, W_hh, b_ih, b_hh, Wo, bo, out);
}

// Round 7
// 773.194 us; speedup vs baseline: 1.1199x; 1.0867x over previous
//
#include <hip/hip_runtime.h>

// OnlineDenoisingAutoencoder: LSTM(B=2048, T=2048, in=1, proj=16, H=32)
// R13 = R11 dual-chain + INSTRUCTION-granular A/B interleave.
// R12 post-mortem: region-level sched_barrier fences CANNOT create overlap
// because wave issue is strictly in-order -- within a region each dependent
// hop (add->rcp->fma->permlane->fma->exp2) stalls the wave, and the next
// region's independent ops sit behind it in program order (VGPR fell to 56:
// compiler kept one chain live at a time). Measured: issue 650 cyc/pair
// (2x325, matches estimate), stall 334/pair = both chains' latency tails
// serialized. Fix: the post-dot scalar tail is written as ALTERNATING A/B
// instruction pairs, each pinned with sched_barrier(0), so every dependent
// hop has the other chain's op (+2 issue cyc) between it and its producer.
// Dots remain two dense blocks (P2's 32 independent fdot2 cover P1's exp2).
// Also: merged single DPP reduce (R6-proven): lanes 0-31 reduce batch A,
// 32-63 batch B via one v_cndmask; writers lane 31 (A) / 63 (B).
// Tell for success: VGPR ~100-130 (both chains live), busy ~90%+.
// History: R6 665 (single chain, 237 stall); R7 796 (phase-locked 2/SIMD);
// R8 728 / R9 1264 (reg-exchange 2-3x static); R10 770 (stagger transient);
// R11 882 (compiler serialized chains); R12 840 (region fences can't beat
// in-order issue).

#define BB 2048
#define TT 2048
#define HH 32

typedef _Float16 h2 __attribute__((ext_vector_type(2)));
typedef unsigned int uint2v __attribute__((ext_vector_type(2)));

#define SB() __builtin_amdgcn_sched_barrier(0)

template <int CTRL>
__device__ __forceinline__ float dpp_add(float v) {
    int s = __builtin_amdgcn_update_dpp(0, __float_as_int(v), CTRL, 0xf, 0xf, true);
    return v + __int_as_float(s);
}

struct HVec { h2 v[16]; };

__device__ __forceinline__ HVec gather_h(const _Float16* base) {
    const float4* p = (const float4*)base;   // 64 B = 4 x ds_read_b128 (broadcast)
    float4 q0 = p[0], q1 = p[1], q2 = p[2], q3 = p[3];
    HVec r;
    r.v[0]  = __builtin_bit_cast(h2, q0.x); r.v[1]  = __builtin_bit_cast(h2, q0.y);
    r.v[2]  = __builtin_bit_cast(h2, q0.z); r.v[3]  = __builtin_bit_cast(h2, q0.w);
    r.v[4]  = __builtin_bit_cast(h2, q1.x); r.v[5]  = __builtin_bit_cast(h2, q1.y);
    r.v[6]  = __builtin_bit_cast(h2, q1.z); r.v[7]  = __builtin_bit_cast(h2, q1.w);
    r.v[8]  = __builtin_bit_cast(h2, q2.x); r.v[9]  = __builtin_bit_cast(h2, q2.y);
    r.v[10] = __builtin_bit_cast(h2, q2.z); r.v[11] = __builtin_bit_cast(h2, q2.w);
    r.v[12] = __builtin_bit_cast(h2, q3.x); r.v[13] = __builtin_bit_cast(h2, q3.y);
    r.v[14] = __builtin_bit_cast(h2, q3.z); r.v[15] = __builtin_bit_cast(h2, q3.w);
    return r;
}

__global__ __launch_bounds__(256) void lstm_fused_kernel(
    const float* __restrict__ x_seq,  // [B,T,1]
    const float* __restrict__ Wp,     // [16,1]
    const float* __restrict__ bp,     // [16]
    const float* __restrict__ W_ih,   // [128,16]
    const float* __restrict__ W_hh,   // [128,32]
    const float* __restrict__ b_ih,   // [128]
    const float* __restrict__ b_hh,   // [128]
    const float* __restrict__ Wo,     // [1,32]
    const float* __restrict__ bo,     // [1]
    float* __restrict__ out)          // [B,T,1] fp32
{
    const int tid  = threadIdx.x;
    const int wave = tid >> 6;
    const int lane = tid & 63;
    const int half = lane >> 5;      // gate-pair selector: 0 -> (i,g), 1 -> (f,o)
    const int j    = lane & 31;      // hidden index this lane owns
    const int b0   = blockIdx.x * 8 + wave * 2;   // batches b0 (A), b0+1 (B)

    // PyTorch gate row order: i=[0,32), f=[32,64), g=[64,96), o=[96,128)
    const int rA = half * HH + j;            // i (half0) or f (half1) -- sigmoid
    const int rB = 2 * HH + half * HH + j;   // g (half0, tanh) or o (half1, sigmoid)

    const float LOG2E = 1.44269504088896340736f;
    const float mA  = -LOG2E;                        // sigmoid rows (i, f)
    const float mBv = half ? -LOG2E : -2.0f * LOG2E; // o : g
    const float aB  = half ? 1.0f : 2.0f;            // gate-B finish consts
    const float bBc = half ? 0.0f : -1.0f;

    // ---- W_hh rows (2 gates per lane), PRESCALED, shared by both batches ----
    h2 wA[16], wB[16];
    {
        const float2* pA = (const float2*)(W_hh + rA * HH);
        const float2* pB = (const float2*)(W_hh + rB * HH);
#pragma unroll
        for (int k = 0; k < 16; ++k) {
            float2 a = pA[k], q = pB[k];
            wA[k].x = (_Float16)(a.x * mA);  wA[k].y = (_Float16)(a.y * mA);
            wB[k].x = (_Float16)(q.x * mBv); wB[k].y = (_Float16)(q.y * mBv);
        }
    }

    // ---- collapse input pipeline (prescaled): pre-act_s = dot_s + x*xA_ + kA_ ----
    float xA_ = 0.f, kA_ = 0.f, xB_ = 0.f, kB_ = 0.f;
#pragma unroll
    for (int p = 0; p < 16; ++p) {
        float wpv = Wp[p], bpv = bp[p];
        float wa = W_ih[rA * 16 + p], wb = W_ih[rB * 16 + p];
        xA_ = fmaf(wa, wpv, xA_);  kA_ = fmaf(wa, bpv, kA_);
        xB_ = fmaf(wb, wpv, xB_);  kB_ = fmaf(wb, bpv, kB_);
    }
    kA_ = (kA_ + b_ih[rA] + b_hh[rA]) * mA;
    kB_ = (kB_ + b_ih[rB] + b_hh[rB]) * mBv;
    xA_ *= mA;
    xB_ *= mBv;

    const float M2 = -2.0f * LOG2E;   // tanh(c) exp2 multiplier
    const float woj = Wo[j];
    const float bo0 = bo[0];

    // per-(wave,batch,half) h replica, fp16, 64 B each
    __shared__ __align__(16) _Float16 hsh[4][2][2][HH];
    _Float16* baseA = &hsh[wave][0][half][0];
    _Float16* baseB = &hsh[wave][1][half][0];
    baseA[j] = (_Float16)0.0f;
    baseB[j] = (_Float16)0.0f;

    float cA = 0.0f, cB = 0.0f;
    const float* xpA = x_seq + (size_t)b0 * TT;
    const float* xpB = x_seq + (size_t)(b0 + 1) * TT;
    // merged-reduce writer: lane 31 -> batch A, lane 63 -> batch B
    float* opw = out + (size_t)(b0 + half) * TT;

    HVec vA = gather_h(baseA);            // zeros (same-wave DS order)
    HVec vB = gather_h(baseB);
    float4 x4A = *(const float4*)(xpA);
    float4 x4B = *(const float4*)(xpB);

    for (int t = 0; t < TT; t += 4) {
        const int tn = (t + 4 < TT) ? (t + 4) : t;
        float4 x4An = *(const float4*)(xpA + tn);   // prefetch next group
        float4 x4Bn = *(const float4*)(xpB + tn);
        float outv[4];
#pragma unroll
        for (int u = 0; u < 4; ++u) {
            float xvA = (u == 0) ? x4A.x : (u == 1) ? x4A.y : (u == 2) ? x4A.z : x4A.w;
            float xvB = (u == 0) ? x4B.x : (u == 1) ? x4B.y : (u == 2) ? x4B.z : x4B.w;

            // ================= P1: dots A + exp2 A =================
            float sAa0 = kA_, sAa1 = xvA * xA_;
            float sAb0 = kB_, sAb1 = xvA * xB_;
#pragma unroll
            for (int k = 0; k < 16; k += 2) {
                h2 h0 = vA.v[k], h1 = vA.v[k + 1];
                sAa0 = __builtin_amdgcn_fdot2(wA[k],     h0, sAa0, false);
                sAb0 = __builtin_amdgcn_fdot2(wB[k],     h0, sAb0, false);
                sAa1 = __builtin_amdgcn_fdot2(wA[k + 1], h1, sAa1, false);
                sAb1 = __builtin_amdgcn_fdot2(wB[k + 1], h1, sAb1, false);
            }
            float eAa = __builtin_amdgcn_exp2f(sAa0 + sAa1);   // prescaled args
            float eAb = __builtin_amdgcn_exp2f(sAb0 + sAb1);
            SB();

            // ================= P2: dots B + exp2 B =================
            // (32 independent fdot2 cover P1's exp2 latency)
            float sBa0 = kA_, sBa1 = xvB * xA_;
            float sBb0 = kB_, sBb1 = xvB * xB_;
#pragma unroll
            for (int k = 0; k < 16; k += 2) {
                h2 h0 = vB.v[k], h1 = vB.v[k + 1];
                sBa0 = __builtin_amdgcn_fdot2(wA[k],     h0, sBa0, false);
                sBb0 = __builtin_amdgcn_fdot2(wB[k],     h0, sBb0, false);
                sBa1 = __builtin_amdgcn_fdot2(wA[k + 1], h1, sBa1, false);
                sBb1 = __builtin_amdgcn_fdot2(wB[k + 1], h1, sBb1, false);
            }
            float eBa = __builtin_amdgcn_exp2f(sBa0 + sBa1);
            float eBb = __builtin_amdgcn_exp2f(sBb0 + sBb1);
            SB();

            // ===== interleaved scalar tail: alternate A/B, pin each pair =====
            float tAa = 1.0f + eAa;            float tBa = 1.0f + eBa;  SB();
            float tAb = 1.0f + eAb;            float tBb = 1.0f + eBb;  SB();
            float rAa = __builtin_amdgcn_rcpf(tAa);
            float rBa = __builtin_amdgcn_rcpf(tBa);                     SB();
            float rAb = __builtin_amdgcn_rcpf(tAb);
            float rBb = __builtin_amdgcn_rcpf(tBb);                     SB();
            // gate-a act = rAa/rBa (sigmoid); gate-b finish:
            float BactA = fmaf(aB, rAb, bBc);  float BactB = fmaf(aB, rBb, bBc); SB();
            // exchanges: r[0] = lower-half value both halves, r[1] = upper-half
            uint2v xAa = __builtin_amdgcn_permlane32_swap(
                __float_as_uint(rAa), __float_as_uint(rAa), false, false);
            uint2v xBa = __builtin_amdgcn_permlane32_swap(
                __float_as_uint(rBa), __float_as_uint(rBa), false, false);  SB();
            uint2v xAb = __builtin_amdgcn_permlane32_swap(
                __float_as_uint(BactA), __float_as_uint(BactA), false, false);
            uint2v xBb = __builtin_amdgcn_permlane32_swap(
                __float_as_uint(BactB), __float_as_uint(BactB), false, false); SB();
            float ivA = __uint_as_float(xAa[0]), fvA = __uint_as_float(xAa[1]);
            float ivB = __uint_as_float(xBa[0]), fvB = __uint_as_float(xBa[1]);
            float gvA = __uint_as_float(xAb[0]), ovA = __uint_as_float(xAb[1]);
            float gvB = __uint_as_float(xBb[0]), ovB = __uint_as_float(xBb[1]);
            float mulA = ivA * gvA;            float mulB = ivB * gvB;   SB();
            cA = fmaf(fvA, cA, mulA);          cB = fmaf(fvB, cB, mulB); SB();
            float uAc = cA * M2;               float uBc = cB * M2;      SB();
            float ecA = __builtin_amdgcn_exp2f(uAc);
            float ecB = __builtin_amdgcn_exp2f(uBc);                     SB();
            float vAc = 1.0f + ecA;            float vBc = 1.0f + ecB;   SB();
            float rAc = __builtin_amdgcn_rcpf(vAc);
            float rBc = __builtin_amdgcn_rcpf(vBc);                      SB();
            float thA = fmaf(2.0f, rAc, -1.0f);
            float thB = fmaf(2.0f, rBc, -1.0f);                          SB();
            float hAs = ovA * thA;             float hBs = ovB * thB;    SB();
            baseA[j] = (_Float16)hAs;          baseB[j] = (_Float16)hBs; SB();
            vA = gather_h(baseA);              vB = gather_h(baseB);     SB();

            // ===== merged output reduce (R6-proven tree): lanes 0-31 sum A,
            // lanes 32-63 sum B; totals land at lane 31 (A) and 63 (B) =====
            float hsel = half ? hBs : hAs;     // one v_cndmask
            float po = woj * hsel;
            po = dpp_add<0x111>(po);
            po = dpp_add<0x112>(po);
            po = dpp_add<0x114>(po);
            po = dpp_add<0x118>(po);
            po = dpp_add<0x142>(po);
            outv[u] = po + bo0;
        }
        if ((lane & 31) == 31) {
            *(float4*)(opw + t) = make_float4(outv[0], outv[1], outv[2], outv[3]);
        }
        x4A = x4An;
        x4B = x4Bn;
    }
}

extern "C" void kernel_launch(void* const* d_in, const int* in_sizes, int n_in,
                              void* d_out, int out_size, void* d_ws, size_t ws_size,
                              hipStream_t stream) {
    const float* x_seq = (const float*)d_in[0];
    const float* Wp    = (const float*)d_in[1];
    const float* bp    = (const float*)d_in[2];
    const float* W_ih  = (const float*)d_in[3];
    const float* W_hh  = (const float*)d_in[4];
    const float* b_ih  = (const float*)d_in[5];
    const float* b_hh  = (const float*)d_in[6];
    const float* Wo    = (const float*)d_in[7];
    const float* bo    = (const float*)d_in[8];
    float* out = (float*)d_out;

    dim3 grid(BB / 8);   // 4 waves/block, 2 batches/wave -> 1024 waves (1/SIMD)
    dim3 block(256);
    lstm_fused_kernel<<<grid, block, 0, stream>>>(
        x_seq, Wp, bp, W_ih, W_hh, b_ih, b_hh, Wo, bo, out);
}